// Round 7
// baseline (89.662 us; speedup 1.0000x reference)
//
#include <hip/hip_runtime.h>
#include <math.h>

// RBF kernel matrix: cov[i][j] = exp(lv - 0.5*||(x_i - xx_j) * inv_scale||^2)
// Log2-domain expansion (v_exp_f32 = exp2 applied directly):
//   W[d]   = inv_scale[d]^2 * log2(e)
//   B[j,d] = xx[j,d] * W[d]
//   c[j]   = lv*log2e - 0.5 * sum_d xx[j,d]^2 * W[d]
//   cov    = exp2(h_i + c_j + sum_d x[i,d] * B[j,d])
//
// R6 theory (resubmitted after infra failure): the ~21us (3.2 TB/s) plateau
// across R0/R1/R2/R4/R5 is HBM write efficiency lost to temporal address
// incoherence: 2048 short-lived tile blocks spray 4KB chunks at 16KB stride
// across the whole 67MB at once. The 5.9 TB/s harness fill is a persistent
// grid-stride kernel sweeping one narrow linear window. R6 reproduces that
// shape: 512 persistent blocks (2/CU, co-resident), each iteration writes
// ONE FULL 16KB contiguous row; the grid's active window is a contiguous
// ~8MB band advancing in 8 steps. Per-thread column state (16 fixed cols:
// B[16][8], c[16]) computed once, reused for all rows.

constexpr int D    = 8;    // feature dim (fixed by reference)
constexpr int BLK  = 256;  // threads per block
constexpr int NQ   = 4;    // row quarters: M == BLK*4*NQ == 4096 (exact fit)
constexpr int GRID = 512;  // persistent blocks: 2 per CU, all co-resident

typedef float f32x4 __attribute__((ext_vector_type(4)));

__global__ __launch_bounds__(BLK) void rbf_kernel(
    const float* __restrict__ x,         // [N, D]
    const float* __restrict__ xx,        // [M, D]
    const float* __restrict__ log_scale, // [D]
    const float* __restrict__ log_var,   // [1]
    float* __restrict__ out,             // [N, M]
    int N, int M)
{
    const int t = threadIdx.x;
    if (M != BLK * 4 * NQ) return;  // problem fixes M=4096; exact-fit kernel

    constexpr float LOG2E = 1.4426950408889634f;
    float w[D];
#pragma unroll
    for (int d = 0; d < D; ++d) {
        const float s = __expf(-log_scale[d]);  // 1/scale
        w[d] = s * s * LOG2E;                   // log2e folded in
    }
    const float lv2 = log_var[0] * LOG2E;

    // This thread's 16 fixed columns: j(s,k) = s*1024 + t*4 + k.
    // B/c computed once per block, reused for every row.
    float B[NQ * 4][D], c[NQ * 4];
#pragma unroll
    for (int s = 0; s < NQ; ++s) {
#pragma unroll
        for (int k = 0; k < 4; ++k) {
            const int j   = s * (BLK * 4) + t * 4 + k;
            const int idx = s * 4 + k;
            const float4* p = (const float4*)(xx + (size_t)j * D);
            const float4 a = p[0], b = p[1];
            const float v[D] = {a.x, a.y, a.z, a.w, b.x, b.y, b.z, b.w};
            float q = 0.f;
#pragma unroll
            for (int d = 0; d < D; ++d) {
                B[idx][d] = v[d] * w[d];
                q = fmaf(v[d], B[idx][d], q);
            }
            c[idx] = fmaf(-0.5f, q, lv2);
        }
    }

    // Persistent sweep: block b writes rows b, b+GRID, b+2*GRID, ...
    // Each iteration emits one full 16KB contiguous row; grid-wide the
    // active window is a contiguous band advancing linearly (fill-like).
    for (int i = blockIdx.x; i < N; i += gridDim.x) {
        const float4* px = (const float4*)(x + (size_t)i * D);  // wave-uniform
        const float4 a = px[0], b = px[1];
        const float xv[D] = {a.x, a.y, a.z, a.w, b.x, b.y, b.z, b.w};
        float q = 0.f;
#pragma unroll
        for (int d = 0; d < D; ++d) q = fmaf(xv[d] * w[d], xv[d], q);
        const float h = -0.5f * q;

        float res[NQ * 4];
#pragma unroll
        for (int idx = 0; idx < NQ * 4; ++idx) {
            float e = h + c[idx];
#pragma unroll
            for (int d = 0; d < D; ++d) e = fmaf(xv[d], B[idx][d], e);
            res[idx] = __builtin_amdgcn_exp2f(e);
        }

        // 4 back-to-back 1KB wave-stores; row is fully contiguous in memory.
        float* rowp = out + (size_t)i * M;
#pragma unroll
        for (int s = 0; s < NQ; ++s) {
            const f32x4 o = {res[s * 4 + 0], res[s * 4 + 1],
                             res[s * 4 + 2], res[s * 4 + 3]};
            *(f32x4*)(rowp + s * (BLK * 4) + t * 4) = o;
        }
    }
}

extern "C" void kernel_launch(void* const* d_in, const int* in_sizes, int n_in,
                              void* d_out, int out_size, void* d_ws, size_t ws_size,
                              hipStream_t stream) {
    const float* x  = (const float*)d_in[0];
    const float* xx = (const float*)d_in[1];
    const float* ls = (const float*)d_in[2];
    const float* lv = (const float*)d_in[3];
    float* out      = (float*)d_out;

    const int N = in_sizes[0] / D;
    const int M = in_sizes[1] / D;

    dim3 block(BLK, 1, 1);
    dim3 grid(GRID, 1, 1);
    rbf_kernel<<<grid, block, 0, stream>>>(x, xx, ls, lv, out, N, M);
}